// Round 8
// baseline (380.244 us; speedup 1.0000x reference)
//
#include <hip/hip_runtime.h>

typedef unsigned short u16;
typedef _Float16 f16;
typedef f16    f16x8  __attribute__((ext_vector_type(8)));
typedef float  f32x4  __attribute__((ext_vector_type(4)));
typedef u16    u16x4  __attribute__((ext_vector_type(4)));
typedef u16    u16x8  __attribute__((ext_vector_type(8)));

#define MFMA16(a, b, c) __builtin_amdgcn_mfma_f32_16x16x32_f16(a, b, c, 0, 0, 0)

template <int V> struct ic { static constexpr int v = V; };

// fp32 -> fp16 RNE (v_cvt_f16_f32), bit pattern as u16
__device__ __forceinline__ u16 f2h(float f) {
    f16 h = (f16)f;
    return __builtin_bit_cast(u16, h);
}

// pack two fp32 -> fp16x2 in one u32
__device__ __forceinline__ unsigned pkh(float a, float b) {
    union { f16 h[2]; unsigned u; } c;
    c.h[0] = (f16)a;
    c.h[1] = (f16)b;
    return c.u;
}

// async global->LDS, 16B per lane; LDS dest is wave-uniform base + lane*16
__device__ __forceinline__ void gll16(const void* g, void* l) {
    __builtin_amdgcn_global_load_lds((__attribute__((address_space(1))) void*)(void*)(g),
                                     (__attribute__((address_space(3))) void*)(l), 16, 0, 0);
}

// waitcnt immediates (gfx9: vmcnt[3:0]|[15:14], expcnt[6:4], lgkm[11:8])
#define WC_VM3_LG0  0x0073   // vmcnt(3)  + lgkmcnt(0)
#define WC_VM0_LG0  0x0070   // vmcnt(0)  + lgkmcnt(0)
#define WC_VM4_LG0  0x0074   // vmcnt(4)  + lgkmcnt(0)
#define WC_VM6_LG0  0x0076   // vmcnt(6)  + lgkmcnt(0)
#define WC_VM8_LG0  0x0078   // vmcnt(8)  + lgkmcnt(0)
#define WC_LG0      0xC07F   // lgkmcnt(0) only
#define WC_VM8      0x0F78   // vmcnt(8) only
#define WC_VM6      0x0F76   // vmcnt(6) only

// ------------- fused prep: weight casts fp32->fp16 + RMSNorm ----------------
__global__ __launch_bounds__(256) void prep_k(const float* __restrict__ x,
                                              const float* __restrict__ w,
                                              u16* __restrict__ xn,
                                              const float* __restrict__ wq,
                                              u16* __restrict__ oq,
                                              const float* __restrict__ wo,
                                              u16* __restrict__ oo) {
    const int bid = blockIdx.x;
    if (bid >= 4096) {
        const int cb = bid - 4096;
        const float* in;
        u16* out;
        size_t i;
        if (cb < 12288) { in = wq; out = oq; i = ((size_t)cb * 256 + threadIdx.x) * 4; }
        else            { in = wo; out = oo; i = ((size_t)(cb - 12288) * 256 + threadIdx.x) * 4; }
        float4 v = *(const float4*)(in + i);
        u16x4 o;
        o.x = f2h(v.x); o.y = f2h(v.y); o.z = f2h(v.z); o.w = f2h(v.w);
        *(u16x4*)(out + i) = o;
        return;
    }
    const int row = bid;
    const float* xr = x + (size_t)row * 2048;
    const int base = threadIdx.x * 8;
    float4 v0 = *(const float4*)(xr + base);
    float4 v1 = *(const float4*)(xr + base + 4);
    float ss = v0.x * v0.x + v0.y * v0.y + v0.z * v0.z + v0.w * v0.w +
               v1.x * v1.x + v1.y * v1.y + v1.z * v1.z + v1.w * v1.w;
#pragma unroll
    for (int off = 32; off >= 1; off >>= 1) ss += __shfl_xor(ss, off);
    __shared__ float red[4];
    const int wave = threadIdx.x >> 6, lane = threadIdx.x & 63;
    if (lane == 0) red[wave] = ss;
    __syncthreads();
    float tot = red[0] + red[1] + red[2] + red[3];
    float sc = rsqrtf(tot * (1.0f / 2048.0f) + 1e-6f);
    const float* wp = w + base;
    u16x4 a, b;
    a.x = f2h(v0.x * sc * wp[0]); a.y = f2h(v0.y * sc * wp[1]);
    a.z = f2h(v0.z * sc * wp[2]); a.w = f2h(v0.w * sc * wp[3]);
    b.x = f2h(v1.x * sc * wp[4]); b.y = f2h(v1.y * sc * wp[5]);
    b.z = f2h(v1.z * sc * wp[6]); b.w = f2h(v1.w * sc * wp[7]);
    u16* o = xn + (size_t)row * 2048 + base;
    *(u16x4*)(o)     = a;
    *(u16x4*)(o + 4) = b;
}

// ---- QKV GEMM: 256x256 tile, 2-phase deep pipe (R8) ------------------------
// C = A[M,K]*B[N,K]^T, fp16. 512 thr = 8 waves (2M x 4N), per-wave 128x64
// (acc[8][4]) -> per-FLOP LDS traffic x0.75 vs 128x256 (the LDS pipe was the
// measured wall: 64KB reads + 24KB writes/tile vs 621cy MFMA). BK=32,
// QUAD-buffered 4 x 32KB = 128KB, 1 block/CU, grid 384 (16m x 24n, 1.5 rounds).
// Per K-tile: 2 phases of 16 MFMA (m201 density). P0(t): read fA_hi(t),
// stage A(t+3), MFMA acc[0..3] (fA_lo x fB). P1(t): counted vm gate for tile
// t+1 (6 -> tail 4 -> 0; queue verified by induction: at gate(t) outstanding
// = {A(t+2),B(t+2),A(t+3)} x2gll after draining tile t+1), read fA_lo(t+1)+
// fB(t+1), stage B(t+3), MFMA acc[4..7] (fA_hi x fB). fB ping-pongs (fBa/fBb).
// Every barrier preceded by lgkm(0) (+vm gate) + sched_barrier(0): R7's
// no-ds-in-flight-at-barrier invariant. sched_barrier(0) also pins reads+
// stages BEFORE the MFMA cluster (R5's +13us lever). setprio(1) around MFMA.
// Buffer-overwrite safety: stageX(t+3) targets buf (t-1)&3; its last readers
// (fA_hi(t-1) in P0(t-1)) drained before the P1(t-1)-entry barrier, one full
// barrier before the stage issues.
// Epilogue: R1-verified per-wave XOR-swizzled [64][64] restage x2 halves.
__global__ __launch_bounds__(512, 2) void gemm_qkv8(const u16* __restrict__ A,
                                                    const u16* __restrict__ B,
                                                    u16* __restrict__ q,
                                                    u16* __restrict__ kk,
                                                    u16* __restrict__ vt) {
    __shared__ __align__(16) u16 lds_[65536];  // 128KB: buf b at b*16384; A [0,8192) B [8192,16384)
    const int tid = threadIdx.x;
    const int wave = tid >> 6, lane = tid & 63;
    const int wm = wave >> 2, wn = wave & 3;
    const int quad = lane >> 4, l16 = lane & 15;
    constexpr int K = 2048, NT = 64;

    // XCD swizzle: 16m x 24n grid; xcd owns bn in [xcd*3, xcd*3+3)
    const int bid = blockIdx.x;
    const int xcd = bid & 7, ci = bid >> 3;       // ci in [0,48)
    const int bm = ci & 15, bn = xcd * 3 + (ci >> 4);
    const int m0 = bm * 256, n0 = bn * 256;

    // staging: 512 threads, row tid>>2 per 128-row chunk, granule-permuted src
    const int gsrc = (tid & 3) ^ ((tid >> 3) & 3);
    const u16* Ag = A + (size_t)(m0 + (tid >> 2)) * K + gsrc * 8;
    const u16* Bg = B + (size_t)(n0 + (tid >> 2)) * K + gsrc * 8;
    const int wofs = wave * 512;                  // per-wave gll dest offset (u16)

    auto stageA = [&](int t) {                    // 2 gll: rows 0-127, 128-255
        u16* d = lds_ + (t & 3) * 16384 + wofs;
        const u16* g = Ag + t * 32;
        gll16(g, d);
        gll16(g + (size_t)128 * K, d + 4096);
    };
    auto stageB = [&](int t) {
        u16* d = lds_ + (t & 3) * 16384 + 8192 + wofs;
        const u16* g = Bg + t * 32;
        gll16(g, d);
        gll16(g + (size_t)128 * K, d + 4096);
    };

    // fragment offsets (u16): row stride 32; granule pos = quad^((row>>1)&3)
    const int fofs = (quad ^ ((l16 >> 1) & 3)) * 8;
    const int aOff = (wm * 128 + l16) * 32 + fofs;          // + mi*512; hi half +2048
    const int bOff = 8192 + (wn * 64 + l16) * 32 + fofs;    // + ni*512

    f32x4 acc[8][4] = {};

    stageA(0); stageB(0); stageA(1); stageB(1); stageA(2); stageB(2);
    __builtin_amdgcn_s_waitcnt(WC_VM8);           // drain tile 0 (A0,B0 of 12)
    asm volatile("" ::: "memory");
    __builtin_amdgcn_s_barrier();
    asm volatile("" ::: "memory");

    f16x8 fAlo[4], fAhi[4], fBa[4], fBb[4];
    {
        const u16* buf = lds_;
#pragma unroll
        for (int i = 0; i < 4; ++i) fAlo[i] = *(const f16x8*)(buf + aOff + i * 512);
#pragma unroll
        for (int i = 0; i < 4; ++i) fBa[i]  = *(const f16x8*)(buf + bOff + i * 512);
    }

    auto phase0 = [&](int t, f16x8 (&lo)[4], f16x8 (&hi)[4], f16x8 (&fb)[4]) {
        __builtin_amdgcn_s_waitcnt(WC_LG0);       // R7 invariant (also feeds MFMA deps)
        __builtin_amdgcn_sched_barrier(0);
        asm volatile("" ::: "memory");
        __builtin_amdgcn_s_barrier();
        asm volatile("" ::: "memory");
        const u16* buf = lds_ + (t & 3) * 16384;
#pragma unroll
        for (int i = 0; i < 4; ++i) hi[i] = *(const f16x8*)(buf + aOff + 2048 + i * 512);
        if (t + 3 < NT) stageA(t + 3);
        __builtin_amdgcn_sched_barrier(0);        // loads issued BEFORE MFMA cluster
        __builtin_amdgcn_s_setprio(1);
#pragma unroll
        for (int mi = 0; mi < 4; ++mi)
#pragma unroll
            for (int ni = 0; ni < 4; ++ni)
                acc[mi][ni] = MFMA16(lo[mi], fb[ni], acc[mi][ni]);
        __builtin_amdgcn_s_setprio(0);
    };
    auto phase1 = [&](int t, f16x8 (&hi)[4], f16x8 (&fb)[4],
                      f16x8 (&nlo)[4], f16x8 (&nfb)[4]) {
        if (t <= NT - 4)      __builtin_amdgcn_s_waitcnt(WC_VM6_LG0);  // drain tile t+1
        else if (t == NT - 3) __builtin_amdgcn_s_waitcnt(WC_VM4_LG0);
        else                  __builtin_amdgcn_s_waitcnt(WC_VM0_LG0);
        __builtin_amdgcn_sched_barrier(0);
        asm volatile("" ::: "memory");
        __builtin_amdgcn_s_barrier();
        asm volatile("" ::: "memory");
        if (t + 1 < NT) {
            const u16* buf = lds_ + ((t + 1) & 3) * 16384;
#pragma unroll
            for (int i = 0; i < 4; ++i) nlo[i] = *(const f16x8*)(buf + aOff + i * 512);
#pragma unroll
            for (int i = 0; i < 4; ++i) nfb[i] = *(const f16x8*)(buf + bOff + i * 512);
        }
        if (t + 3 < NT) stageB(t + 3);
        __builtin_amdgcn_sched_barrier(0);
        __builtin_amdgcn_s_setprio(1);
#pragma unroll
        for (int mi = 0; mi < 4; ++mi)
#pragma unroll
            for (int ni = 0; ni < 4; ++ni)
                acc[4 + mi][ni] = MFMA16(hi[mi], fb[ni], acc[4 + mi][ni]);
        __builtin_amdgcn_s_setprio(0);
    };

    for (int t = 0; t < NT; t += 2) {
        phase0(t,     fAlo, fAhi, fBa);
        phase1(t,     fAhi, fBa, fAlo, fBb);
        phase0(t + 1, fAlo, fAhi, fBb);
        phase1(t + 1, fAhi, fBb, fAlo, fBa);
    }

    // loop->epilogue: all ds-ops drained, all waves synced before LDS reuse
    __builtin_amdgcn_s_waitcnt(WC_VM0_LG0);
    __builtin_amdgcn_sched_barrier(0);
    asm volatile("" ::: "memory");
    __builtin_amdgcn_s_barrier();
    asm volatile("" ::: "memory");

    const int which = n0 >> 11;                  // 0=q, 1=k, 2=v (uniform)
    const int h0 = (n0 & 2047) >> 7;
    const int b = m0 >> 11;
    const int hw = h0 + (wn >> 1);
    const int bh = b * 16 + hw;
    const int dh0 = (wn & 1) * 64;
    const int t0base = (m0 & 2047) + wm * 128;
    u16* stg = lds_ + wave * 4096;               // 8KB/wave, bytes [0,64K)
    const int lr = lane >> 3, lc = lane & 7;
    const float scl = (which == 0) ? 0.12751791061880135f : 1.0f;  // SCALE*log2(e)
#pragma unroll
    for (int sub = 0; sub < 2; ++sub) {
        const int t0 = t0base + sub * 64;
        if (which == 2) {
            // stage transposed: row = dh_local, col = t_local
#pragma unroll
            for (int mi = 0; mi < 4; ++mi)
#pragma unroll
                for (int ni = 0; ni < 4; ++ni)
#pragma unroll
                    for (int r = 0; r < 4; ++r) {
                        int row = ni * 16 + l16;
                        int col = mi * 16 + quad * 4 + r;
                        stg[row * 64 + (((col >> 3) ^ (row & 7)) * 8) + (col & 7)] =
                            f2h(acc[sub * 4 + mi][ni][r]);
                    }
#pragma unroll
            for (int i = 0; i < 8; ++i) {
                int row = i * 8 + lr;
                u16x8 vv = *(const u16x8*)(stg + row * 64 + ((lc ^ (row & 7)) * 8));
                *(u16x8*)(vt + ((size_t)bh * 128 + dh0 + row) * 2048 + t0 + lc * 8) = vv;
            }
        } else {
            u16* dst0 = (which == 0 ? q : kk);
#pragma unroll
            for (int mi = 0; mi < 4; ++mi)
#pragma unroll
                for (int ni = 0; ni < 4; ++ni)
#pragma unroll
                    for (int r = 0; r < 4; ++r) {
                        int row = mi * 16 + quad * 4 + r;
                        int col = ni * 16 + l16;
                        stg[row * 64 + (((col >> 3) ^ (row & 7)) * 8) + (col & 7)] =
                            f2h(acc[sub * 4 + mi][ni][r] * scl);
                    }
#pragma unroll
            for (int i = 0; i < 8; ++i) {
                int row = i * 8 + lr;
                u16x8 vv = *(const u16x8*)(stg + row * 64 + ((lc ^ (row & 7)) * 8));
                *(u16x8*)(dst0 + ((size_t)bh * 2048 + t0 + row) * 128 + dh0 + lc * 8) = vv;
            }
        }
        if (sub == 0) { asm volatile("" ::: "memory"); __builtin_amdgcn_s_waitcnt(WC_LG0); }
    }
}

// ------- out-proj GEMM: 128x256 tile, single barrier per K-tile (R7) --------
__global__ __launch_bounds__(512, 2) void gemm_dp(const u16* __restrict__ A,
                                                  const u16* __restrict__ B,
                                                  int K, int N,
                                                  float* __restrict__ Cf) {
    __shared__ __align__(16) u16 lds_[49152];
    const int tid = threadIdx.x;
    const int wave = tid >> 6, lane = tid & 63;
    const int wm = wave >> 2, wn = wave & 3;
    const int quad = lane >> 4, l16 = lane & 15;

    const int bid = blockIdx.x;
    const int xcd = bid & 7, ci = bid >> 3;
    const int bm = ci, bn = xcd;                 // 32 x 8 grid, 256 blocks
    const int m0 = bm * 128, n0 = bn * 256;

    const int gsrc = (tid & 3) ^ ((tid >> 3) & 3);
    const u16* Ag = A + (size_t)(m0 + (tid >> 2)) * K + gsrc * 8;
    const u16* Bg = B + (size_t)(n0 + (tid >> 2)) * K + gsrc * 8;
    u16* ldsW = lds_ + wave * 512;

    auto stage = [&](int t) {
        u16* d = ldsW + (t & 3) * 12288;
        const u16* ga = Ag + t * 32;
        const u16* gb = Bg + t * 32;
        gll16(ga, d);
        gll16(gb, d + 4096);
        gll16(gb + (size_t)128 * K, d + 8192);
    };

    const int fofs = (quad ^ ((l16 >> 1) & 3)) * 8;
    const int aOff = (wm * 64 + l16) * 32 + fofs;
    const int bOff = 4096 + (wn * 64 + l16) * 32 + fofs;

    auto ldfrag = [&](int t, f16x8 (&fa)[4], f16x8 (&fb)[4]) {
        const u16* buf = lds_ + (t & 3) * 12288;
#pragma unroll
        for (int mi = 0; mi < 4; ++mi) fa[mi] = *(const f16x8*)(buf + aOff + mi * 512);
#pragma unroll
        for (int ni = 0; ni < 4; ++ni) fb[ni] = *(const f16x8*)(buf + bOff + ni * 512);
    };

    f32x4 acc[4][4] = {};
    const int NT = K >> 5;

    stage(0); stage(1); stage(2);
    __builtin_amdgcn_s_waitcnt(WC_VM6);
    asm volatile("" ::: "memory");
    __builtin_amdgcn_s_barrier();
    asm volatile("" ::: "memory");

    f16x8 fA0[4], fB0[4], fA1[4], fB1[4];
    ldfrag(0, fA0, fB0);

    auto body = [&](int t, f16x8 (&ca)[4], f16x8 (&cb)[4],
                    f16x8 (&na)[4], f16x8 (&nb)[4]) {
        if (t + 1 < NT) {
            if (t + 2 < NT) __builtin_amdgcn_s_waitcnt(WC_VM3_LG0);
            else            __builtin_amdgcn_s_waitcnt(WC_VM0_LG0);
        } else {
            __builtin_amdgcn_s_waitcnt(WC_LG0);
        }
        __builtin_amdgcn_sched_barrier(0);
        asm volatile("" ::: "memory");
        __builtin_amdgcn_s_barrier();
        asm volatile("" ::: "memory");
        if (t + 1 < NT) ldfrag(t + 1, na, nb);
        if (t + 3 < NT) stage(t + 3);
        __builtin_amdgcn_sched_barrier(0);
        __builtin_amdgcn_s_setprio(1);
#pragma unroll
        for (int mi = 0; mi < 4; ++mi)
#pragma unroll
            for (int ni = 0; ni < 4; ++ni)
                acc[mi][ni] = MFMA16(ca[mi], cb[ni], acc[mi][ni]);
        __builtin_amdgcn_s_setprio(0);
    };

    for (int t = 0; t < NT; t += 2) {
        body(t,     fA0, fB0, fA1, fB1);
        body(t + 1, fA1, fB1, fA0, fB0);
    }

#pragma unroll
    for (int mi = 0; mi < 4; ++mi)
#pragma unroll
        for (int ni = 0; ni < 4; ++ni) {
            int row = m0 + wm * 64 + mi * 16 + quad * 4;
            int col = n0 + wn * 64 + ni * 16 + l16;
#pragma unroll
            for (int r = 0; r < 4; ++r)
                Cf[(size_t)(row + r) * N + col] = acc[mi][ni][r];
        }
}

// ---------------- flash attention, causal (R7-verified form) -----------------
__global__ __launch_bounds__(256, 2) void flash_k(const u16* __restrict__ Q,
                                                  const u16* __restrict__ Kx,
                                                  const u16* __restrict__ Vt,
                                                  u16* __restrict__ Y) {
    __shared__ __align__(16) u16 lK0[64 * 128];
    __shared__ __align__(16) u16 lK1[64 * 128];
    __shared__ __align__(16) u16 lV0[128 * 64];
    __shared__ __align__(16) u16 lV1[128 * 64];
    __shared__ __align__(16) u16 lP[8 * 16 * 64];
    const int tid = threadIdx.x;
    const int wave = tid >> 6, lane = tid & 63;
    const int quad = lane >> 4, l16 = lane & 15;
    const int lx7 = l16 & 7;
    const int bh = blockIdx.y;
    const int qt = (blockIdx.y < 16) ? blockIdx.x : (15 - blockIdx.x);
    const int qt0 = qt * 128;

    f16x8 qf[2][4];
#pragma unroll
    for (int mi = 0; mi < 2; ++mi) {
        const u16* qrow = Q + ((size_t)bh * 2048 + qt0 + mi * 64 + wave * 16 + l16) * 128 + quad * 8;
#pragma unroll
        for (int ks = 0; ks < 4; ++ks) qf[mi][ks] = *(const f16x8*)(qrow + ks * 32);
    }

    f32x4 oacc[2][8] = {};
    float rsum[2] = {0.0f, 0.0f};
    const int qn0 = qt0 + wave * 16 + l16;
    const int qn1 = qn0 + 64;

    const u16* kgbase = Kx + (size_t)bh * 2048 * 128;
    const u16* vgbase = Vt + (size_t)bh * 128 * 2048;
    const int nkt = 2 * qt + 2;

    auto stage = [&](int kt0, u16* dK, u16* dV) {
#pragma unroll
        for (int i = 0; i < 4; ++i) {
            int row = wave * 16 + i * 4 + (lane >> 4);
            int g = (lane & 15) ^ (row & 7);
            gll16(kgbase + (size_t)(kt0 + row) * 128 + g * 8, dK + wave * 2048 + i * 512);
        }
#pragma unroll
        for (int i = 0; i < 4; ++i) {
            int row = wave * 32 + i * 8 + (lane >> 3);
            int g = (lane & 7) ^ (row & 7);
            gll16(vgbase + (size_t)row * 2048 + kt0 + g * 8, dV + wave * 2048 + i * 512);
        }
    };

    auto compute = [&](auto mode_c, const u16* bK, const u16* bV, int kt0) {
        constexpr int MODE = decltype(mode_c)::v;
        f32x4 sT[2][4] = {};
#pragma unroll
        for (int mc = 0; mc < 4; ++mc)
#pragma unroll
            for (int ks = 0; ks < 4; ++ks) {
                f16x8 kb = *(const f16x8*)(bK + (mc * 16 + l16) * 128 +
                                           (((4 * ks + quad) ^ lx7) * 8));
                if (MODE != 2) sT[0][mc] = MFMA16(kb, qf[0][ks], sT[0][mc]);
                sT[1][mc] = MFMA16(kb, qf[1][ks], sT[1][mc]);
            }

#pragma unroll
        for (int mi = 0; mi < 2; ++mi) {
            if (MODE == 2 && mi == 0) continue;
            constexpr bool DIAG0 = (MODE == 1);
            constexpr bool DIAG1 = (MODE == 2);
            const bool DIAG = (mi == 0) ? DIAG0 : DIAG1;
            const int qn = (mi == 0) ? qn0 : qn1;
            u16* pw = lP + (wave * 2 + mi) * 1024 + l16 * 64 + (quad & 1) * 4;
#pragma unroll
            for (int mc = 0; mc < 4; ++mc) {
                float p0 = __builtin_exp2f(sT[mi][mc][0]);
                float p1 = __builtin_exp2f(sT[mi][mc][1]);
                float p2 = __builtin_exp2f(sT[mi][mc][2]);
                float p3 = __builtin_exp2f(sT[mi][mc][3]);
                if (DIAG) {
                    int kg = kt0 + mc * 16 + quad * 4;
                    p0 = (kg + 0 > qn) ? 0.0f : p0;
                    p1 = (kg + 1 > qn) ? 0.0f : p1;
                    p2 = (kg + 2 > qn) ? 0.0f : p2;
                    p3 = (kg + 3 > qn) ? 0.0f : p3;
                }
                rsum[mi] += (p0 + p1) + (p2 + p3);
                int gp = (((2 * mc + (quad >> 1)) ^ lx7) * 8);
                *(unsigned*)(pw + gp)     = pkh(p0, p1);
                *(unsigned*)(pw + gp + 2) = pkh(p2, p3);
            }
        }

        f16x8 pf0[2], pf1[2];
#pragma unroll
        for (int k2 = 0; k2 < 2; ++k2) {
            if (MODE != 2)
                pf0[k2] = *(const f16x8*)(lP + (wave * 2 + 0) * 1024 + l16 * 64 +
                                          (((4 * k2 + quad) ^ lx7) * 8));
            pf1[k2] = *(const f16x8*)(lP + (wave * 2 + 1) * 1024 + l16 * 64 +
                                      (((4 * k2 + quad) ^ lx7) * 8));
        }
#pragma unroll
        for (int dt = 0; dt < 8; ++dt)
#pragma unroll
            for (int k2 = 0; k2 < 2; ++k2) {
                f16x8 vb = *(const f16x8*)(bV + (dt * 16 + l16) * 64 +
                                           (((4 * k2 + quad) ^ lx7) * 8));
                if (MODE != 2) oacc[0][dt] = MFMA16(pf0[k2], vb, oacc[0][dt]);
                oacc[1][dt] = MFMA16(pf1[k2], vb, oacc[1][dt]);
            }
    };

    stage(0, lK0, lV0);
    for (int kt = 0; kt < nkt; ++kt) {
        const int kt0 = kt * 64;
        if (kt + 1 < nkt) {
            if ((kt & 1) == 0) stage(kt0 + 64, lK1, lV1);
            else               stage(kt0 + 64, lK0, lV0);
            __builtin_amdgcn_s_waitcnt(WC_VM8_LG0);
        } else {
            __builtin_amdgcn_s_waitcnt(WC_VM0_LG0);
        }
        __builtin_amdgcn_sched_barrier(0);
        asm volatile("" ::: "memory");
        __builtin_amdgcn_s_barrier();
        asm volatile("" ::: "memory");
        const u16* bK = (kt & 1) ? lK1 : lK0;
        const u16* bV = (kt & 1) ? lV1 : lV0;
        if (kt < 2 * qt)       compute(ic<0>{}, bK, bV, kt0);
        else if (kt == 2 * qt) compute(ic<1>{}, bK, bV, kt0);
        else                   compute(ic<2>{}, bK, bV, kt0);
        __builtin_amdgcn_s_waitcnt(WC_LG0);
        __builtin_amdgcn_sched_barrier(0);
        asm volatile("" ::: "memory");
        __builtin_amdgcn_s_barrier();
        asm volatile("" ::: "memory");
    }

    float* rb = (float*)(lP + wave * 1024);
#pragma unroll
    for (int mi = 0; mi < 2; ++mi) {
        float rs = rsum[mi];
        rs += __shfl_xor(rs, 16);
        rs += __shfl_xor(rs, 32);
        if (quad == 0) rb[mi * 16 + l16] = rs;
    }
    const int b = bh >> 4, h = bh & 15;
#pragma unroll
    for (int mi = 0; mi < 2; ++mi) {
        f32x4 rsv = *(const f32x4*)(rb + mi * 16 + quad * 4);
#pragma unroll
        for (int r = 0; r < 4; ++r) {
            float inv = 1.0f / rsv[r];
            int t = qt0 + mi * 64 + wave * 16 + quad * 4 + r;
            u16* yr = Y + ((size_t)b * 2048 + t) * 2048 + h * 128;
#pragma unroll
            for (int dt = 0; dt < 8; ++dt) yr[dt * 16 + l16] = f2h(oacc[mi][dt][r] * inv);
        }
    }
}

extern "C" void kernel_launch(void* const* d_in, const int* in_sizes, int n_in,
                              void* d_out, int out_size, void* d_ws, size_t ws_size,
                              hipStream_t stream) {
    const float* x    = (const float*)d_in[0];
    const float* nw   = (const float*)d_in[1];
    const float* wqkv = (const float*)d_in[2];
    const float* wout = (const float*)d_in[3];
    float* out = (float*)d_out;

    // workspace layout (u16 elements)
    u16* ws = (u16*)d_ws;
    u16* xn      = ws;                      //  4096*2048
    u16* wqkv_b  = xn + 8388608;            //  6144*2048
    u16* wout_b  = wqkv_b + 12582912;       //  2048*2048
    u16* q       = wout_b + 4194304;        //  [32][2048][128]
    u16* kk      = q + 8388608;             //  [32][2048][128]
    u16* vt      = kk + 8388608;            //  [32][128][2048]
    u16* y       = vt + 8388608;            //  [4096][2048]

    prep_k<<<20480, 256, 0, stream>>>(x, nw, xn, wqkv, wqkv_b, wout, wout_b);

    gemm_qkv8<<<384, 512, 0, stream>>>(xn, wqkv_b, q, kk, vt);

    dim3 gf(16, 32);
    flash_k<<<gf, 256, 0, stream>>>(q, kk, vt, y);

    gemm_dp<<<256, 512, 0, stream>>>(y, wout_b, 2048, 2048, out);
}